// Round 4
// baseline (1201.316 us; speedup 1.0000x reference)
//
#include <hip/hip_runtime.h>
#include <hip/hip_cooperative_groups.h>
#include <math.h>

// TGV-2 PDHG, B=2, H=W=256, T=128.
// R4: single persistent cooperative kernel. 16 rounds x 8 trapezoid
// iterations, grid.sync() between rounds (15 syncs) instead of 16 launches.
// Geometry unchanged from R3: 16x16 tile + halo 8 => 32x32 region, 512
// blocks (= 2 per CU, exactly co-resident), 256 threads (4 waves), thread
// owns a 1x4 strip, all 12 fields in registers, LDS only for halo exchange
// (aligned b128, conflict-free). Interior threads keep state in registers
// across rounds (their 16x16 is exact); only rim threads reload after sync.

namespace cg = cooperative_groups;

namespace {

constexpr int kN = 2 * 256 * 256;
constexpr float kTau = 0.28867513459481287f;  // 1/sqrt(12) (f32)
constexpr float kSigma = kTau;
constexpr float kInv1pTau = 1.0f / (1.0f + kTau);

constexpr int R = 32;           // region side
constexpr int A = R * R;        // 1024 floats per LDS array
constexpr int PAD = 64;         // rim-overread safety pads (front/back)
constexpr int TILE = 16;
constexpr int HALO = 8;         // iterations per round
constexpr int ROUNDS = 128 / HALO;  // 16
constexpr int NTHREADS = R * (R / 4);  // 256 = 4 waves

__device__ __forceinline__ float4 ld4(const float* p) {
  return *reinterpret_cast<const float4*>(p);
}
__device__ __forceinline__ void st4v(float* p, const float* a) {
  float4 v;
  v.x = a[0]; v.y = a[1]; v.z = a[2]; v.w = a[3];
  *reinterpret_cast<float4*>(p) = v;
}
__device__ __forceinline__ float msel(bool m, float x) { return m ? x : 0.f; }

// ws layout: 10 arrays of kN floats: ub, v1, v2, vb1, vb2, p1, p2, q11, q22, q12
__global__ __launch_bounds__(256) void init_kernel(const float* __restrict__ f,
                                                   float* __restrict__ u,
                                                   float* __restrict__ ws) {
  int n = blockIdx.x * 256 + threadIdx.x;
  float fv = f[n];
  u[n] = fv;
  ws[n] = fv;  // ub = u0
#pragma unroll
  for (int i = 1; i < 10; ++i) ws[i * kN + n] = 0.f;
}

__global__ __launch_bounds__(NTHREADS, 2) void tgv_persist(
    const float* __restrict__ f, const float* __restrict__ rp,
    float* __restrict__ ug, float* __restrict__ ws) {
  float* ubg = ws + 0 * kN;
  float* v1g = ws + 1 * kN;
  float* v2g = ws + 2 * kN;
  float* vb1g = ws + 3 * kN;
  float* vb2g = ws + 4 * kN;
  float* p1g = ws + 5 * kN;
  float* p2g = ws + 6 * kN;
  float* q11g = ws + 7 * kN;
  float* q22g = ws + 8 * kN;
  float* q12g = ws + 9 * kN;

  __shared__ __align__(16) float smem[PAD + 8 * A + PAD];
  float* ubS = smem + PAD;
  float* vb1S = ubS + A;
  float* vb2S = vb1S + A;
  float* p1S = vb2S + A;
  float* p2S = p1S + A;
  float* q11S = p2S + A;
  float* q22S = q11S + A;
  float* q12S = q22S + A;

  const int tid = threadIdx.x;
  const int r = tid >> 3;       // region row 0..31
  const int c = (tid & 7) * 4;  // region col (float4-aligned)
  const int rc = r * R + c;

  const int gi = blockIdx.y * TILE + r - HALO;  // global row (may be OOB)
  const int gj = blockIdx.x * TILE + c - HALO;  // global col (float4 in/out)
  const bool inImg = ((unsigned)gi < 256u) && ((unsigned)gj < 256u);
  const bool isInterior =
      (r >= HALO && r < HALO + TILE && c >= HALO && c < HALO + TILE);
  const int base = blockIdx.z * 65536 + gi * 256 + gj;

  const float alpha0 = rp[0];
  const float alpha1 = rp[1];

  // image-boundary masks (global coords; garbage positions don't matter)
  const bool hasD = (gi != 255);
  const bool hasU = (gi != 0);

  float u_[4], ub_[4], v1_[4], v2_[4], vb1_[4], vb2_[4];
  float p1_[4], p2_[4], q11_[4], q22_[4], q12_[4], f_[4];

#define LOADV(dst, src)                                       \
  {                                                           \
    float4 t_ = ld4((src) + base);                            \
    dst[0] = t_.x; dst[1] = t_.y; dst[2] = t_.z; dst[3] = t_.w; \
  }
#define LOADSTATE      \
  LOADV(u_, ug)        \
  LOADV(ub_, ubg)      \
  LOADV(v1_, v1g)      \
  LOADV(v2_, v2g)      \
  LOADV(vb1_, vb1g)    \
  LOADV(vb2_, vb2g)    \
  LOADV(p1_, p1g)      \
  LOADV(p2_, p2g)      \
  LOADV(q11_, q11g)    \
  LOADV(q22_, q22g)    \
  LOADV(q12_, q12g)

  if (inImg) {
    LOADV(f_, f)
    LOADSTATE
  } else {
#pragma unroll
    for (int e = 0; e < 4; ++e) {
      f_[e] = 0.f; u_[e] = 0.f; ub_[e] = 0.f;
      v1_[e] = 0.f; v2_[e] = 0.f; vb1_[e] = 0.f; vb2_[e] = 0.f;
      p1_[e] = 0.f; p2_[e] = 0.f; q11_[e] = 0.f; q22_[e] = 0.f; q12_[e] = 0.f;
    }
  }

  cg::grid_group grid = cg::this_grid();

  for (int round = 0; round < ROUNDS; ++round) {
    if (round) {
      grid.sync();
      // rim threads re-read neighbor-produced state; interior is exact in regs
      if (inImg && !isInterior) {
        LOADSTATE
      }
    }

    for (int t = 0; t < HALO; ++t) {
      // ---- publish dual halos (ub, vb) ----
      st4v(ubS + rc, ub_);
      st4v(vb1S + rc, vb1_);
      st4v(vb2S + rc, vb2_);
      __syncthreads();

      // ---- dual ascent + projections (updates p,q in registers) ----
      const float ubX = ld4(ubS + rc + 4).x;  // right-edge neighbor, aligned
      const float vb1X = ld4(vb1S + rc + 4).x;
      const float vb2X = ld4(vb2S + rc + 4).x;
      float4 td;
      td = ld4(ubS + rc + R);
      const float ubD[4] = {td.x, td.y, td.z, td.w};
      td = ld4(vb1S + rc + R);
      const float vb1D[4] = {td.x, td.y, td.z, td.w};
      td = ld4(vb2S + rc + R);
      const float vb2D[4] = {td.x, td.y, td.z, td.w};

#pragma unroll
      for (int e = 0; e < 4; ++e) {
        const bool hR = (gj + e != 255);
        const float ubr = (e < 3) ? ub_[e + 1] : ubX;
        const float vb1r = (e < 3) ? vb1_[e + 1] : vb1X;
        const float vb2r = (e < 3) ? vb2_[e + 1] : vb2X;

        const float du1 = msel(hasD, ubD[e] - ub_[e]);  // fwd diff axis1 (H)
        const float du2 = msel(hR, ubr - ub_[e]);       // fwd diff axis2 (W)
        float pn1 = p1_[e] + kSigma * (du1 - vb1_[e]);
        float pn2 = p2_[e] + kSigma * (du2 - vb2_[e]);
        float nrm = sqrtf(pn1 * pn1 + pn2 * pn2);
        float sc = alpha1 * __builtin_amdgcn_rcpf(fmaxf(alpha1, nrm));
        p1_[e] = pn1 * sc;
        p2_[e] = pn2 * sc;

        const float e11 = msel(hasD, vb1D[e] - vb1_[e]);
        const float e22 = msel(hR, vb2r - vb2_[e]);
        const float e12 =
            0.5f * (msel(hR, vb1r - vb1_[e]) + msel(hasD, vb2D[e] - vb2_[e]));
        float qn1 = q11_[e] + kSigma * e11;
        float qn2 = q22_[e] + kSigma * e22;
        float qn3 = q12_[e] + kSigma * e12;
        nrm = sqrtf(qn1 * qn1 + qn2 * qn2 + 2.f * qn3 * qn3);
        sc = alpha0 * __builtin_amdgcn_rcpf(fmaxf(alpha0, nrm));
        q11_[e] = qn1 * sc;
        q22_[e] = qn2 * sc;
        q12_[e] = qn3 * sc;
      }

      // ---- publish primal halos (new p, q) ----
      st4v(p1S + rc, p1_);
      st4v(p2S + rc, p2_);
      st4v(q11S + rc, q11_);
      st4v(q22S + rc, q22_);
      st4v(q12S + rc, q12_);
      __syncthreads();

      // ---- primal descent + over-relaxation ----
      float4 tu;
      tu = ld4(p1S + rc - R);
      const float p1U[4] = {tu.x, tu.y, tu.z, tu.w};
      tu = ld4(q11S + rc - R);
      const float q11U[4] = {tu.x, tu.y, tu.z, tu.w};
      tu = ld4(q12S + rc - R);
      const float q12U[4] = {tu.x, tu.y, tu.z, tu.w};
      const float p2Lx = ld4(p2S + rc - 4).w;  // left-edge neighbor, aligned
      const float q22Lx = ld4(q22S + rc - 4).w;
      const float q12Lx = ld4(q12S + rc - 4).w;

#pragma unroll
      for (int e = 0; e < 4; ++e) {
        const bool hR = (gj + e != 255);
        const bool hL = (e == 0) ? (gj != 0) : true;
        const float p2l = (e == 0) ? p2Lx : p2_[e - 1];
        const float q22l = (e == 0) ? q22Lx : q22_[e - 1];
        const float q12l = (e == 0) ? q12Lx : q12_[e - 1];

        const float divp = msel(hasD, p1_[e]) - msel(hasU, p1U[e]) +
                           msel(hR, p2_[e]) - msel(hL, p2l);
        const float un = (u_[e] + kTau * divp + kTau * f_[e]) * kInv1pTau;
        ub_[e] = 2.f * un - u_[e];
        u_[e] = un;

        const float c1 = msel(hasD, q11_[e]) - msel(hasU, q11U[e]) +
                         msel(hR, q12_[e]) - msel(hL, q12l);
        const float c2 = msel(hasD, q12_[e]) - msel(hasU, q12U[e]) +
                         msel(hR, q22_[e]) - msel(hL, q22l);
        const float v1n = v1_[e] + kTau * (p1_[e] + c1);
        const float v2n = v2_[e] + kTau * (p2_[e] + c2);
        vb1_[e] = 2.f * v1n - v1_[e];
        v1_[e] = v1n;
        vb2_[e] = 2.f * v2n - v2_[e];
        v2_[e] = v2n;
      }
    }

    // ---- store interior 16x16 (exact after 8 iters) ----
    if (isInterior) {
      st4v(ug + base, u_);
      st4v(ubg + base, ub_);
      st4v(v1g + base, v1_);
      st4v(v2g + base, v2_);
      st4v(vb1g + base, vb1_);
      st4v(vb2g + base, vb2_);
      st4v(p1g + base, p1_);
      st4v(p2g + base, p2_);
      st4v(q11g + base, q11_);
      st4v(q22g + base, q22_);
      st4v(q12g + base, q12_);
    }
  }
#undef LOADSTATE
#undef LOADV
}

}  // namespace

extern "C" void kernel_launch(void* const* d_in, const int* in_sizes, int n_in,
                              void* d_out, int out_size, void* d_ws,
                              size_t ws_size, hipStream_t stream) {
  const float* f = (const float*)d_in[0];
  const float* rp = (const float*)d_in[1];  // [alpha0, alpha1]
  // d_in[2] is T = 128 (fixed; trip count must be static for graph capture).

  float* u = (float*)d_out;
  float* ws = (float*)d_ws;

  hipLaunchKernelGGL(init_kernel, dim3(kN / 256), dim3(256), 0, stream, f, u,
                     ws);

  dim3 grid(256 / TILE, 256 / TILE, 2);  // 16 x 16 x 2 = 512 blocks, 2 per CU
  dim3 block(NTHREADS);
  void* args[] = {(void*)&f, (void*)&rp, (void*)&u, (void*)&ws};
  hipLaunchCooperativeKernel((void*)tgv_persist, grid, block, args, 0, stream);
}

// Round 5
// 1077.685 us; speedup vs baseline: 1.1147x; 1.1147x over previous
//
#include <hip/hip_runtime.h>
#include <math.h>

// TGV-2 PDHG, B=2, H=W=256, T=128.
// R5: persistent cooperative kernel with a MANUAL inline grid barrier.
// R4's cg::grid.sync() lowered to a device-lib call (__ockl_grid_sync) which
// forced the 48-float register state to scratch (VGPR=56, FETCH 170MB, 3x
// slower). The barrier here is pure inline atomics: one atomicAdd + spin per
// block on a monotonic counter, __threadfence release/acquire. No call =>
// state stays in VGPRs.
// Geometry (validated R3/R4): 16x16 tile + halo 8 => 32x32 region, 512 blocks
// (2/CU, exactly co-resident under cooperative launch), 256 threads (4 waves),
// each thread owns a 1x4 strip, all 12 fields in registers, LDS only for halo
// exchange (aligned b128). 16 rounds x 8 iterations, 15 grid barriers.
// Interior threads keep state in registers across rounds; rim threads reload.

namespace {

constexpr int kN = 2 * 256 * 256;
constexpr float kTau = 0.28867513459481287f;  // 1/sqrt(12) (f32)
constexpr float kSigma = kTau;
constexpr float kInv1pTau = 1.0f / (1.0f + kTau);

constexpr int R = 32;           // region side
constexpr int A = R * R;        // 1024 floats per LDS array
constexpr int PAD = 64;         // rim-overread safety pads (front/back)
constexpr int TILE = 16;
constexpr int HALO = 8;         // iterations per round
constexpr int ROUNDS = 128 / HALO;  // 16
constexpr int NTHREADS = R * (R / 4);  // 256 = 4 waves
constexpr unsigned NBLOCKS = 16 * 16 * 2;  // 512

__device__ unsigned g_ctr;  // grid-barrier counter (zeroed by init_kernel)

__device__ __forceinline__ float4 ld4(const float* p) {
  return *reinterpret_cast<const float4*>(p);
}
__device__ __forceinline__ void st4v(float* p, const float* a) {
  float4 v;
  v.x = a[0]; v.y = a[1]; v.z = a[2]; v.w = a[3];
  *reinterpret_cast<float4*>(p) = v;
}
__device__ __forceinline__ float msel(bool m, float x) { return m ? x : 0.f; }

// Inline grid barrier: all blocks must be co-resident (cooperative launch).
// target = (number of barrier episodes so far) * NBLOCKS; counter only grows.
__device__ __forceinline__ void grid_barrier(unsigned target) {
  __syncthreads();  // drains this block's stores (vmcnt(0) before s_barrier)
  if (threadIdx.x == 0) {
    __threadfence();  // release: block's stores visible device-wide
    atomicAdd(&g_ctr, 1u);  // device-scope by default on gfx950
    while (__hip_atomic_load(&g_ctr, __ATOMIC_RELAXED,
                             __HIP_MEMORY_SCOPE_AGENT) < target) {
      __builtin_amdgcn_s_sleep(2);
    }
    __threadfence();  // acquire: invalidate stale cached lines
  }
  __syncthreads();
}

// ws layout: 10 arrays of kN floats: ub, v1, v2, vb1, vb2, p1, p2, q11, q22, q12
__global__ __launch_bounds__(256) void init_kernel(const float* __restrict__ f,
                                                   float* __restrict__ u,
                                                   float* __restrict__ ws) {
  int n = blockIdx.x * 256 + threadIdx.x;
  if (n == 0) g_ctr = 0u;
  float fv = f[n];
  u[n] = fv;
  ws[n] = fv;  // ub = u0
#pragma unroll
  for (int i = 1; i < 10; ++i) ws[i * kN + n] = 0.f;
}

__global__ __launch_bounds__(NTHREADS, 2) void tgv_persist(
    const float* __restrict__ f, const float* __restrict__ rp,
    float* __restrict__ ug, float* __restrict__ ws) {
  float* ubg = ws + 0 * kN;
  float* v1g = ws + 1 * kN;
  float* v2g = ws + 2 * kN;
  float* vb1g = ws + 3 * kN;
  float* vb2g = ws + 4 * kN;
  float* p1g = ws + 5 * kN;
  float* p2g = ws + 6 * kN;
  float* q11g = ws + 7 * kN;
  float* q22g = ws + 8 * kN;
  float* q12g = ws + 9 * kN;

  __shared__ __align__(16) float smem[PAD + 8 * A + PAD];
  float* ubS = smem + PAD;
  float* vb1S = ubS + A;
  float* vb2S = vb1S + A;
  float* p1S = vb2S + A;
  float* p2S = p1S + A;
  float* q11S = p2S + A;
  float* q22S = q11S + A;
  float* q12S = q22S + A;

  const int tid = threadIdx.x;
  const int r = tid >> 3;       // region row 0..31
  const int c = (tid & 7) * 4;  // region col (float4-aligned)
  const int rc = r * R + c;

  const int gi = blockIdx.y * TILE + r - HALO;  // global row (may be OOB)
  const int gj = blockIdx.x * TILE + c - HALO;  // global col (float4 in/out)
  const bool inImg = ((unsigned)gi < 256u) && ((unsigned)gj < 256u);
  const bool isInterior =
      (r >= HALO && r < HALO + TILE && c >= HALO && c < HALO + TILE);
  const int base = blockIdx.z * 65536 + gi * 256 + gj;

  const float alpha0 = rp[0];
  const float alpha1 = rp[1];

  // image-boundary masks (global coords; garbage positions don't matter)
  const bool hasD = (gi != 255);
  const bool hasU = (gi != 0);

  float u_[4], ub_[4], v1_[4], v2_[4], vb1_[4], vb2_[4];
  float p1_[4], p2_[4], q11_[4], q22_[4], q12_[4], f_[4];

#define LOADV(dst, src)                                       \
  {                                                           \
    float4 t_ = ld4((src) + base);                            \
    dst[0] = t_.x; dst[1] = t_.y; dst[2] = t_.z; dst[3] = t_.w; \
  }
#define LOADSTATE      \
  LOADV(u_, ug)        \
  LOADV(ub_, ubg)      \
  LOADV(v1_, v1g)      \
  LOADV(v2_, v2g)      \
  LOADV(vb1_, vb1g)    \
  LOADV(vb2_, vb2g)    \
  LOADV(p1_, p1g)      \
  LOADV(p2_, p2g)      \
  LOADV(q11_, q11g)    \
  LOADV(q22_, q22g)    \
  LOADV(q12_, q12g)

  if (inImg) {
    LOADV(f_, f)
    LOADSTATE
  } else {
#pragma unroll
    for (int e = 0; e < 4; ++e) {
      f_[e] = 0.f; u_[e] = 0.f; ub_[e] = 0.f;
      v1_[e] = 0.f; v2_[e] = 0.f; vb1_[e] = 0.f; vb2_[e] = 0.f;
      p1_[e] = 0.f; p2_[e] = 0.f; q11_[e] = 0.f; q22_[e] = 0.f; q12_[e] = 0.f;
    }
  }

  for (int round = 0; round < ROUNDS; ++round) {
    if (round) {
      grid_barrier((unsigned)round * NBLOCKS);
      // rim threads re-read neighbor-produced state; interior is exact in regs
      if (inImg && !isInterior) {
        LOADSTATE
      }
    }

    for (int t = 0; t < HALO; ++t) {
      // ---- publish dual halos (ub, vb) ----
      st4v(ubS + rc, ub_);
      st4v(vb1S + rc, vb1_);
      st4v(vb2S + rc, vb2_);
      __syncthreads();

      // ---- dual ascent + projections (updates p,q in registers) ----
      const float ubX = ld4(ubS + rc + 4).x;  // right-edge neighbor, aligned
      const float vb1X = ld4(vb1S + rc + 4).x;
      const float vb2X = ld4(vb2S + rc + 4).x;
      float4 td;
      td = ld4(ubS + rc + R);
      const float ubD[4] = {td.x, td.y, td.z, td.w};
      td = ld4(vb1S + rc + R);
      const float vb1D[4] = {td.x, td.y, td.z, td.w};
      td = ld4(vb2S + rc + R);
      const float vb2D[4] = {td.x, td.y, td.z, td.w};

#pragma unroll
      for (int e = 0; e < 4; ++e) {
        const bool hR = (gj + e != 255);
        const float ubr = (e < 3) ? ub_[e + 1] : ubX;
        const float vb1r = (e < 3) ? vb1_[e + 1] : vb1X;
        const float vb2r = (e < 3) ? vb2_[e + 1] : vb2X;

        const float du1 = msel(hasD, ubD[e] - ub_[e]);  // fwd diff axis1 (H)
        const float du2 = msel(hR, ubr - ub_[e]);       // fwd diff axis2 (W)
        float pn1 = p1_[e] + kSigma * (du1 - vb1_[e]);
        float pn2 = p2_[e] + kSigma * (du2 - vb2_[e]);
        float nrm = sqrtf(pn1 * pn1 + pn2 * pn2);
        float sc = alpha1 * __builtin_amdgcn_rcpf(fmaxf(alpha1, nrm));
        p1_[e] = pn1 * sc;
        p2_[e] = pn2 * sc;

        const float e11 = msel(hasD, vb1D[e] - vb1_[e]);
        const float e22 = msel(hR, vb2r - vb2_[e]);
        const float e12 =
            0.5f * (msel(hR, vb1r - vb1_[e]) + msel(hasD, vb2D[e] - vb2_[e]));
        float qn1 = q11_[e] + kSigma * e11;
        float qn2 = q22_[e] + kSigma * e22;
        float qn3 = q12_[e] + kSigma * e12;
        nrm = sqrtf(qn1 * qn1 + qn2 * qn2 + 2.f * qn3 * qn3);
        sc = alpha0 * __builtin_amdgcn_rcpf(fmaxf(alpha0, nrm));
        q11_[e] = qn1 * sc;
        q22_[e] = qn2 * sc;
        q12_[e] = qn3 * sc;
      }

      // ---- publish primal halos (new p, q) ----
      st4v(p1S + rc, p1_);
      st4v(p2S + rc, p2_);
      st4v(q11S + rc, q11_);
      st4v(q22S + rc, q22_);
      st4v(q12S + rc, q12_);
      __syncthreads();

      // ---- primal descent + over-relaxation ----
      float4 tu;
      tu = ld4(p1S + rc - R);
      const float p1U[4] = {tu.x, tu.y, tu.z, tu.w};
      tu = ld4(q11S + rc - R);
      const float q11U[4] = {tu.x, tu.y, tu.z, tu.w};
      tu = ld4(q12S + rc - R);
      const float q12U[4] = {tu.x, tu.y, tu.z, tu.w};
      const float p2Lx = ld4(p2S + rc - 4).w;  // left-edge neighbor, aligned
      const float q22Lx = ld4(q22S + rc - 4).w;
      const float q12Lx = ld4(q12S + rc - 4).w;

#pragma unroll
      for (int e = 0; e < 4; ++e) {
        const bool hR = (gj + e != 255);
        const bool hL = (e == 0) ? (gj != 0) : true;
        const float p2l = (e == 0) ? p2Lx : p2_[e - 1];
        const float q22l = (e == 0) ? q22Lx : q22_[e - 1];
        const float q12l = (e == 0) ? q12Lx : q12_[e - 1];

        const float divp = msel(hasD, p1_[e]) - msel(hasU, p1U[e]) +
                           msel(hR, p2_[e]) - msel(hL, p2l);
        const float un = (u_[e] + kTau * divp + kTau * f_[e]) * kInv1pTau;
        ub_[e] = 2.f * un - u_[e];
        u_[e] = un;

        const float c1 = msel(hasD, q11_[e]) - msel(hasU, q11U[e]) +
                         msel(hR, q12_[e]) - msel(hL, q12l);
        const float c2 = msel(hasD, q12_[e]) - msel(hasU, q12U[e]) +
                         msel(hR, q22_[e]) - msel(hL, q22l);
        const float v1n = v1_[e] + kTau * (p1_[e] + c1);
        const float v2n = v2_[e] + kTau * (p2_[e] + c2);
        vb1_[e] = 2.f * v1n - v1_[e];
        v1_[e] = v1n;
        vb2_[e] = 2.f * v2n - v2_[e];
        v2_[e] = v2n;
      }
    }

    // ---- store interior 16x16 (exact after 8 iters) ----
    if (isInterior) {
      st4v(ug + base, u_);
      st4v(ubg + base, ub_);
      st4v(v1g + base, v1_);
      st4v(v2g + base, v2_);
      st4v(vb1g + base, vb1_);
      st4v(vb2g + base, vb2_);
      st4v(p1g + base, p1_);
      st4v(p2g + base, p2_);
      st4v(q11g + base, q11_);
      st4v(q22g + base, q22_);
      st4v(q12g + base, q12_);
    }
  }
#undef LOADSTATE
#undef LOADV
}

}  // namespace

extern "C" void kernel_launch(void* const* d_in, const int* in_sizes, int n_in,
                              void* d_out, int out_size, void* d_ws,
                              size_t ws_size, hipStream_t stream) {
  const float* f = (const float*)d_in[0];
  const float* rp = (const float*)d_in[1];  // [alpha0, alpha1]
  // d_in[2] is T = 128 (fixed; trip count must be static for graph capture).

  float* u = (float*)d_out;
  float* ws = (float*)d_ws;

  hipLaunchKernelGGL(init_kernel, dim3(kN / 256), dim3(256), 0, stream, f, u,
                     ws);

  dim3 grid(256 / TILE, 256 / TILE, 2);  // 16 x 16 x 2 = 512 blocks, 2 per CU
  dim3 block(NTHREADS);
  void* args[] = {(void*)&f, (void*)&rp, (void*)&u, (void*)&ws};
  hipLaunchCooperativeKernel((void*)tgv_persist, grid, block, args, 0, stream);
}